// Round 1
// baseline (1234.916 us; speedup 1.0000x reference)
//
#include <hip/hip_runtime.h>

// ---------------- problem constants ----------------
#define WORDS    528384          // 2048 * 258 words = 16,908,288 bits >= 169*100000 hash bins
#define NB_SCAN  258

// ws layout (u32 units)
#define IDX_SCALARS 0                       // [0]=xmax, [1]=n_unique
#define IDX_MASK1   16
#define IDX_MASK2   (16 + WORDS)
#define IDX_COUNTS  (16 + 2*WORDS)          // N u32
#define IDX_WBASE(nrows)  (16 + 2*WORDS + (nrows))
#define IDX_PART(nrows)   (IDX_WBASE(nrows) + WORDS)
#define IDX_PART2(nrows)  (IDX_PART(nrows) + 512)
#define IDX_HRANK(nrows)  (IDX_PART2(nrows) + 512)

__device__ __forceinline__ float tanh_fast(float z) {
    float e = __expf(2.0f * z);                    // e=inf for big z -> 1; e=0 for very neg -> -1
    return 1.0f - 2.0f * __builtin_amdgcn_rcpf(e + 1.0f);
}

// ---- 1) xmax reduction + zero u_sum staging area (out cols 96..127) ----
__global__ void k_init(const int* __restrict__ x, unsigned* __restrict__ scalars,
                       float* __restrict__ out, int n) {
    int g = blockIdx.x * blockDim.x + threadIdx.x;
    int row = g < n ? g : n - 1;
    if (g < n) {
        float4* o4 = (float4*)out + (size_t)row * 32 + 24;
        float4 z = make_float4(0.f, 0.f, 0.f, 0.f);
        #pragma unroll
        for (int q = 0; q < 8; ++q) o4[q] = z;
    }
    unsigned v = (unsigned)x[row];
    #pragma unroll
    for (int off = 32; off > 0; off >>= 1) {
        unsigned o = (unsigned)__shfl_xor((int)v, off);
        v = v > o ? v : o;
    }
    if ((threadIdx.x & 63) == 0) atomicMax(scalars, v);
}

// ---- 2) set presence bit; second mask marks multi-member groups ----
__global__ void k_bits(const int* __restrict__ x, const int* __restrict__ t,
                       const unsigned* __restrict__ scalars,
                       unsigned* __restrict__ mask1, unsigned* __restrict__ mask2, int n) {
    int g = blockIdx.x * blockDim.x + threadIdx.x;
    if (g >= n) return;
    unsigned d = scalars[0] + 1u;
    unsigned h = (unsigned)t[g] * d + (unsigned)x[g];
    unsigned w = h >> 5, bit = 1u << (h & 31);
    unsigned old = atomicOr(&mask1[w], bit);
    if (old & bit) atomicOr(&mask2[w], bit);
}

// ---- 3) prefix-popcount scan over the bitmask (3 kernels) ----
__global__ void k_scan1(const unsigned* __restrict__ mask1, unsigned* __restrict__ part) {
    const int t = threadIdx.x, b = blockIdx.x;
    const unsigned* wp = mask1 + (size_t)b * 2048 + t * 8;
    unsigned s = 0;
    #pragma unroll
    for (int i = 0; i < 8; ++i) s += __popc(wp[i]);
    #pragma unroll
    for (int off = 32; off > 0; off >>= 1) s += (unsigned)__shfl_xor((int)s, off);
    __shared__ unsigned red[4];
    if ((t & 63) == 0) red[t >> 6] = s;
    __syncthreads();
    if (t == 0) part[b] = red[0] + red[1] + red[2] + red[3];
}

__global__ void k_scan2(const unsigned* __restrict__ part, unsigned* __restrict__ part2,
                        unsigned* __restrict__ scalars) {
    const int t = threadIdx.x;
    __shared__ unsigned sm[512];
    unsigned v = (t < NB_SCAN) ? part[t] : 0u;
    sm[t] = v;
    __syncthreads();
    for (int off = 1; off < 512; off <<= 1) {
        unsigned add = (t >= off) ? sm[t - off] : 0u;
        __syncthreads();
        sm[t] += add;
        __syncthreads();
    }
    part2[t] = sm[t] - v;                 // exclusive block offsets
    if (t == 511) scalars[1] = sm[511];   // n_unique
}

__global__ void k_scan3(const unsigned* __restrict__ mask1, const unsigned* __restrict__ part2,
                        unsigned* __restrict__ wbase) {
    const int t = threadIdx.x, b = blockIdx.x;
    const int lane = t & 63, wid = t >> 6;
    const size_t w0 = (size_t)b * 2048 + t * 8;
    unsigned pc[8], tsum = 0;
    #pragma unroll
    for (int i = 0; i < 8; ++i) { pc[i] = __popc(mask1[w0 + i]); tsum += pc[i]; }
    unsigned incl = tsum;
    #pragma unroll
    for (int off = 1; off < 64; off <<= 1) {
        unsigned vv = (unsigned)__shfl_up((int)incl, off);
        if (lane >= off) incl += vv;
    }
    __shared__ unsigned wt[4];
    if (lane == 63) wt[wid] = incl;
    __syncthreads();
    unsigned base = part2[b] + (incl - tsum);
    for (int i = 0; i < wid; ++i) base += wt[i];
    #pragma unroll
    for (int i = 0; i < 8; ++i) { wbase[w0 + i] = base; base += pc[i]; }
}

// ---- 4) scatter user embeddings into out cols 96..127 (by rank), record h + counts ----
// 8 lanes per row; singleton groups (~97%): plain float4 store; multi: fp32 atomics.
__global__ void k_scatter(const int* __restrict__ x, const int* __restrict__ t,
                          const int* __restrict__ u, const float* __restrict__ user_emb,
                          const unsigned* __restrict__ scalars,
                          const unsigned* __restrict__ mask1, const unsigned* __restrict__ mask2,
                          const unsigned* __restrict__ wbase,
                          unsigned* __restrict__ counts, unsigned* __restrict__ hrank,
                          float* __restrict__ out) {
    int g = blockIdx.x * blockDim.x + threadIdx.x;
    int j = g >> 3, q = g & 7;
    unsigned d = scalars[0] + 1u;
    unsigned h = (unsigned)t[j] * d + (unsigned)x[j];
    unsigned w = h >> 5, bp = h & 31;
    unsigned r = wbase[w] + __popc(mask1[w] & ((1u << bp) - 1u));
    unsigned multi = (mask2[w] >> bp) & 1u;
    float4 ue = ((const float4*)user_emb)[(size_t)u[j] * 8 + q];
    if (multi) {
        float* dst = out + (size_t)r * 128 + 96 + q * 4;
        unsafeAtomicAdd(dst + 0, ue.x);
        unsafeAtomicAdd(dst + 1, ue.y);
        unsafeAtomicAdd(dst + 2, ue.z);
        unsafeAtomicAdd(dst + 3, ue.w);
    } else {
        ((float4*)out)[(size_t)r * 32 + 24 + q] = ue;
    }
    if (q == 0) {
        hrank[r] = h | (multi << 31);
        if (multi) atomicAdd(&counts[r], 1u);
    }
}

// ---- 5) fused gather + GEMM(128x128) + tanh, 64-row stripes, two 64-col halves ----
__global__ __launch_bounds__(256, 2) void k_gemm(
    const float* __restrict__ loc_emb, const float* __restrict__ time_emb,
    const float* __restrict__ W, const float* __restrict__ bias,
    const unsigned* __restrict__ scalars, const unsigned* __restrict__ counts,
    const unsigned* __restrict__ hrank, float* __restrict__ out, int n) {
    __shared__ float Asm[128 * 64];   // A[k][row], bank = row%32 -> 2-way (free)
    __shared__ float Wsm[128 * 64];   // WT[k][c_local]
    const int tid = threadIdx.x;
    const unsigned nu = scalars[1];
    const unsigned d  = scalars[0] + 1u;
    const int tx = tid & 15, ty = tid >> 4;       // compute: 4 cols x 4 rows per thread
    const int lrow = tid & 63, jj = tid >> 6;     // staging: 64 lanes x 4 col-chunks
    const int nstripes = (n + 63) >> 6;

    for (int stripe = blockIdx.x; stripe < nstripes; stripe += gridDim.x) {
        // ---- stage A: 64 rows x 128 cols (gathered xtu) ----
        {
            unsigned r = (unsigned)stripe * 64u + (unsigned)lrow;
            float4 vals[8];
            if (r < nu) {
                unsigned hv = hrank[r];
                unsigned h = hv & 0x7FFFFFFFu;
                unsigned xx = h % d, tt = h / d;
                if (jj < 2) {
                    const float4* src = (const float4*)(loc_emb + (size_t)xx * 64 + jj * 32);
                    #pragma unroll
                    for (int s = 0; s < 8; ++s) vals[s] = src[s];
                } else if (jj == 2) {
                    const float4* src = (const float4*)(time_emb + (size_t)tt * 32);
                    #pragma unroll
                    for (int s = 0; s < 8; ++s) vals[s] = src[s];
                } else {
                    float inv = (hv >> 31) ? __builtin_amdgcn_rcpf((float)counts[r]) : 1.0f;
                    const float4* src = (const float4*)(out + (size_t)r * 128 + 96);
                    #pragma unroll
                    for (int s = 0; s < 8; ++s) {
                        float4 v = src[s];
                        vals[s] = make_float4(v.x * inv, v.y * inv, v.z * inv, v.w * inv);
                    }
                }
            } else {
                #pragma unroll
                for (int s = 0; s < 8; ++s) vals[s] = make_float4(0.f, 0.f, 0.f, 0.f);
            }
            #pragma unroll
            for (int s = 0; s < 8; ++s) {
                int c = jj * 32 + s * 4;
                Asm[(c + 0) * 64 + lrow] = vals[s].x;
                Asm[(c + 1) * 64 + lrow] = vals[s].y;
                Asm[(c + 2) * 64 + lrow] = vals[s].z;
                Asm[(c + 3) * 64 + lrow] = vals[s].w;
            }
        }
        for (int cb = 0; cb < 2; ++cb) {
            // stage W half: WT[k][c] = W[cb*64+c][k]
            {
                const float* wsrc = W + (size_t)(cb * 64 + lrow) * 128 + jj * 32;
                #pragma unroll
                for (int s = 0; s < 8; ++s) {
                    float4 v = ((const float4*)wsrc)[s];
                    int k0 = jj * 32 + s * 4;
                    Wsm[(k0 + 0) * 64 + lrow] = v.x;
                    Wsm[(k0 + 1) * 64 + lrow] = v.y;
                    Wsm[(k0 + 2) * 64 + lrow] = v.z;
                    Wsm[(k0 + 3) * 64 + lrow] = v.w;
                }
            }
            __syncthreads();
            float acc[4][4];
            #pragma unroll
            for (int i = 0; i < 4; ++i)
                #pragma unroll
                for (int c = 0; c < 4; ++c) acc[i][c] = 0.f;
            #pragma unroll 8
            for (int k = 0; k < 128; ++k) {
                float4 wv = *(const float4*)&Wsm[k * 64 + tx * 4];
                float4 av = *(const float4*)&Asm[k * 64 + ty * 4];
                acc[0][0] += av.x * wv.x; acc[0][1] += av.x * wv.y; acc[0][2] += av.x * wv.z; acc[0][3] += av.x * wv.w;
                acc[1][0] += av.y * wv.x; acc[1][1] += av.y * wv.y; acc[1][2] += av.y * wv.z; acc[1][3] += av.y * wv.w;
                acc[2][0] += av.z * wv.x; acc[2][1] += av.z * wv.y; acc[2][2] += av.z * wv.z; acc[2][3] += av.z * wv.w;
                acc[3][0] += av.w * wv.x; acc[3][1] += av.w * wv.y; acc[3][2] += av.w * wv.z; acc[3][3] += av.w * wv.w;
            }
            float4 bv = ((const float4*)bias)[cb * 16 + tx];
            #pragma unroll
            for (int i = 0; i < 4; ++i) {
                unsigned r = (unsigned)stripe * 64u + (unsigned)(ty * 4 + i);
                if (r >= (unsigned)n) continue;
                float4 o;
                if (r < nu) {
                    o.x = tanh_fast(acc[i][0] + bv.x);
                    o.y = tanh_fast(acc[i][1] + bv.y);
                    o.z = tanh_fast(acc[i][2] + bv.z);
                    o.w = tanh_fast(acc[i][3] + bv.w);
                } else {
                    o = make_float4(0.f, 0.f, 0.f, 0.f);
                }
                ((float4*)(out + (size_t)r * 128 + cb * 64))[tx] = o;
            }
            __syncthreads();   // protect Wsm (next cb) and Asm (next stripe)
        }
    }
}

extern "C" void kernel_launch(void* const* d_in, const int* in_sizes, int n_in,
                              void* d_out, int out_size, void* d_ws, size_t ws_size,
                              hipStream_t stream) {
    const float* loc_emb  = (const float*)d_in[0];
    const float* time_emb = (const float*)d_in[1];
    const float* user_emb = (const float*)d_in[2];
    const float* W        = (const float*)d_in[3];
    const float* bias     = (const float*)d_in[4];
    const int*   x        = (const int*)d_in[5];
    const int*   t        = (const int*)d_in[6];
    const int*   u        = (const int*)d_in[7];
    float* out = (float*)d_out;
    const int n = in_sizes[5];   // 1,000,000

    unsigned* ws32    = (unsigned*)d_ws;
    unsigned* scalars = ws32 + IDX_SCALARS;
    unsigned* mask1   = ws32 + IDX_MASK1;
    unsigned* mask2   = ws32 + IDX_MASK2;
    unsigned* counts  = ws32 + IDX_COUNTS;
    unsigned* wbase   = ws32 + IDX_WBASE(n);
    unsigned* part    = ws32 + IDX_PART(n);
    unsigned* part2   = ws32 + IDX_PART2(n);
    unsigned* hrank   = ws32 + IDX_HRANK(n);

    const size_t zero_bytes = (size_t)(16 + 2 * WORDS + n) * 4;  // scalars+masks+counts
    hipMemsetAsync(d_ws, 0, zero_bytes, stream);

    int nb = (n + 255) / 256;
    k_init   <<<nb, 256, 0, stream>>>(x, scalars, out, n);
    k_bits   <<<nb, 256, 0, stream>>>(x, t, scalars, mask1, mask2, n);
    k_scan1  <<<NB_SCAN, 256, 0, stream>>>(mask1, part);
    k_scan2  <<<1, 512, 0, stream>>>(part, part2, scalars);
    k_scan3  <<<NB_SCAN, 256, 0, stream>>>(mask1, part2, wbase);
    k_scatter<<<n / 32, 256, 0, stream>>>(x, t, u, user_emb, scalars, mask1, mask2,
                                          wbase, counts, hrank, out);
    k_gemm   <<<1024, 256, 0, stream>>>(loc_emb, time_emb, W, bias, scalars, counts,
                                        hrank, out, n);
}